// Round 2
// baseline (2508.172 us; speedup 1.0000x reference)
//
#include <hip/hip_runtime.h>
#include <hip/hip_cooperative_groups.h>
#include <math.h>

namespace cg = cooperative_groups;

#define IMSIZE 64
#define S_SIZE 4096
#define A_SZ 8
#define C_SZ 10
#define B_SIZE 32
#define SB 128
#define VI_K 30
#define GAMMA 0.99f

// 3x3 SAME conv at (batch b, state s), 2 input channels -> 1 output
__device__ __forceinline__ float conv_at(const float* __restrict__ x,
                                         const float* __restrict__ cw,
                                         float cb, int b, int s) {
    int y = s >> 6, xx = s & 63;
    float acc = cb;
#pragma unroll
    for (int ic = 0; ic < 2; ++ic) {
        const float* xp = x + ((b * 2 + ic) << 12);
#pragma unroll
        for (int ky = 0; ky < 3; ++ky) {
            int yy = y + ky - 1;
            if (yy < 0 || yy >= IMSIZE) continue;
#pragma unroll
            for (int kx = 0; kx < 3; ++kx) {
                int xc = xx + kx - 1;
                if (xc < 0 || xc >= IMSIZE) continue;
                acc = fmaf(xp[(yy << 6) + xc], cw[(ic * 3 + ky) * 3 + kx], acc);
            }
        }
    }
    return acc;
}

// One persistent cooperative kernel:
//   grid = 256 blocks (blockIdx = slice*4 + g), block = 512 threads.
//   Block (slice, g): batch group g (batches 8g..8g+7), states slice*64..+64.
//   LDS: full v for the 8 batches, layout [b8][s] (128 KiB -> 1 block/CU).
//   Thread (w, a) = (tid>>3, tid&7): owns state s = slice*64+w, action a;
//   its 10 transition entries (idx, p) live in registers for all iterations.
__global__ __launch_bounds__(512, 2) void vin_full(
    const float* __restrict__ x,
    const int* __restrict__ s1,
    const int* __restrict__ s2,
    const int* __restrict__ ds_state,
    const int* __restrict__ ds_prob,
    const float* __restrict__ conv_w,
    const float* __restrict__ conv_b,
    const float* __restrict__ pv,
    const float* __restrict__ lin_w,
    const float* __restrict__ lin_b,
    float* __restrict__ vA,
    float* __restrict__ vB,
    float* __restrict__ out)
{
    __shared__ float vld[8 * S_SIZE];   // 128 KiB
    cg::grid_group grid = cg::this_grid();

    const int g = blockIdx.x & 3;
    const int slice = blockIdx.x >> 2;      // == image row y for this block
    const int tid = threadIdx.x;

    // ---- Phase 0: conv init (roles: w = tid>>3 local state, b8 = tid&7) ----
    {
        int w0 = tid >> 3, b80 = tid & 7;
        int s0 = (slice << 6) + w0;
        int b0 = (g << 3) + b80;
        float sar0 = conv_at(x, conv_w, conv_b[0], b0, s0);
        float x1 = x[((b0 * 2 + 1) << 12) + s0];
        float coef0 = GAMMA * (1.0f - 0.1f * x1);
        vld[(unsigned)tid * 2]     = sar0;   // temp exchange buffer
        vld[(unsigned)tid * 2 + 1] = coef0;
    }
    __syncthreads();

    // ---- re-read in (w, a) layout; each thread keeps sar/coef for all 8 b ----
    const int w = tid >> 3, a = tid & 7;
    const int s = (slice << 6) + w;
    float sar_r[8], coef_r[8];
#pragma unroll
    for (int b = 0; b < 8; ++b) {
        sar_r[b]  = vld[(unsigned)(w * 8 + b) * 2];
        coef_r[b] = vld[(unsigned)(w * 8 + b) * 2 + 1];
    }
    // v0 = sar, stored as [g][b][s] (transposed roles for coalesced store)
    {
        int b8 = tid >> 6, sl = tid & 63;
        float v0 = vld[(unsigned)(sl * 8 + b8) * 2];
        vA[(g << 15) + (b8 << 12) + (slice << 6) + sl] = v0;
    }
    // transition row -> registers (persist across all iterations)
    int   lidx[C_SZ];
    float prob[C_SZ];
    {
        const int base_sa = (s * A_SZ + a) * C_SZ;
#pragma unroll
        for (int c = 0; c < C_SZ; ++c) lidx[c] = ds_state[base_sa + c];
#pragma unroll
        for (int c = 0; c < C_SZ; ++c) {
            float p = pv[ds_prob[base_sa + c]];
            prob[c] = fminf(fmaxf(p, 0.0f), 1.0f);
        }
    }
    __threadfence();
    grid.sync();

    // ---- 29 value-iteration steps ----
    float* bufs[2] = { vA, vB };
    for (int k = 0; k < VI_K - 1; ++k) {
        const float* vi = bufs[k & 1];
        float*       vo = bufs[(k + 1) & 1];

        // stage full v of my batch group: 8192 float4, coalesced, linear LDS
        const float4* src = (const float4*)(vi + (g << 15));
        float4* dst = (float4*)vld;
#pragma unroll
        for (int r = 0; r < 16; ++r)
            dst[tid + (r << 9)] = src[tid + (r << 9)];
        __syncthreads();

        // gather-accumulate: acc[b] = sum_c p * v[b][idx]
        float acc[8] = {0.f,0.f,0.f,0.f,0.f,0.f,0.f,0.f};
#pragma unroll
        for (int c = 0; c < C_SZ; ++c) {
            int bs = lidx[c];
            float p = prob[c];
#pragma unroll
            for (int b = 0; b < 8; ++b)
                acc[b] = fmaf(p, vld[(b << 12) + bs], acc[b]);
        }
        float q[8];
#pragma unroll
        for (int b = 0; b < 8; ++b)
            q[b] = fmaf(coef_r[b], acc[b], sar_r[b]);

        // max over a: butterfly within the 8 action-lanes of this state
#pragma unroll
        for (int off = 1; off < 8; off <<= 1) {
#pragma unroll
            for (int b = 0; b < 8; ++b)
                q[b] = fmaxf(q[b], __shfl_xor(q[b], off, 8));
        }
        // lane a writes batch b=a (static select to stay in registers)
        float myv = q[0];
#pragma unroll
        for (int b = 1; b < 8; ++b)
            if (a == b) myv = q[b];
        vo[(g << 15) + (a << 12) + s] = myv;

        __threadfence();
        grid.sync();
    }

    // ---- stage v29 and compute the output tile of this block ----
    {
        const float* vfin = bufs[(VI_K - 1) & 1];
        const float4* src = (const float4*)(vfin + (g << 15));
        float4* dst = (float4*)vld;
#pragma unroll
        for (int r = 0; r < 16; ++r)
            dst[tid + (r << 9)] = src[tid + (r << 9)];
    }
    __syncthreads();

    // 16 outputs per block: batches of group g x 2 sample indices
    if (tid < 16) {
        int b8 = tid >> 1;
        int b  = (g << 3) + b8;
        int j  = (slice << 1) + (tid & 1);
        int t2 = b * SB + j;
        int ss = s1[t2] * IMSIZE + s2[t2];

        float sar = conv_at(x, conv_w, conv_b[0], b, ss);
        float x1 = x[((b * 2 + 1) << 12) + ss];
        float coef = GAMMA * (1.0f - 0.1f * x1);

        float q[A_SZ];
#pragma unroll
        for (int a2 = 0; a2 < A_SZ; ++a2) {
            float accq = 0.0f;
            int bb = (ss * A_SZ + a2) * C_SZ;
#pragma unroll
            for (int c = 0; c < C_SZ; ++c) {
                float p = pv[ds_prob[bb + c]];
                p = fminf(fmaxf(p, 0.0f), 1.0f);
                accq = fmaf(p, vld[(b8 << 12) + ds_state[bb + c]], accq);
            }
            q[a2] = fmaf(coef, accq, sar);
        }
#pragma unroll
        for (int i = 0; i < A_SZ; ++i) {
            float o = lin_b[i] + q[i];
#pragma unroll
            for (int a2 = 0; a2 < A_SZ; ++a2)
                o = fmaf(q[a2], lin_w[i * 8 + a2], o);
            out[t2 * 8 + i] = o;
        }
    }
}

extern "C" void kernel_launch(void* const* d_in, const int* in_sizes, int n_in,
                              void* d_out, int out_size, void* d_ws, size_t ws_size,
                              hipStream_t stream) {
    const float* x        = (const float*)d_in[0];
    const int*   s1       = (const int*)d_in[1];
    const int*   s2       = (const int*)d_in[2];
    const int*   ds_state = (const int*)d_in[3];
    const int*   ds_prob  = (const int*)d_in[4];
    const float* conv_w   = (const float*)d_in[5];
    const float* conv_b   = (const float*)d_in[6];
    const float* pv       = (const float*)d_in[7];
    const float* lin_w    = (const float*)d_in[8];
    const float* lin_b    = (const float*)d_in[9];
    float* out = (float*)d_out;

    const size_t VSZ = (size_t)B_SIZE * S_SIZE * 4;   // 512 KiB
    char* ws = (char*)d_ws;
    float* vA = (float*)(ws);
    float* vB = (float*)(ws + VSZ);

    void* args[] = {
        (void*)&x, (void*)&s1, (void*)&s2, (void*)&ds_state, (void*)&ds_prob,
        (void*)&conv_w, (void*)&conv_b, (void*)&pv, (void*)&lin_w, (void*)&lin_b,
        (void*)&vA, (void*)&vB, (void*)&out
    };
    hipLaunchCooperativeKernel((void*)vin_full, dim3(256), dim3(512),
                               args, 0, stream);
}

// Round 3
// 271.775 us; speedup vs baseline: 9.2289x; 9.2289x over previous
//
#include <hip/hip_runtime.h>
#include <math.h>

#define IMSIZE 64
#define S_SIZE 4096
#define A_SZ 8
#define C_SZ 10
#define B_SIZE 32
#define SB 128
#define VI_K 30
#define GAMMA 0.99f

// v layout (global and LDS): [g][s*8 + b8]  (32 bytes per state -> b128 gathers)

__global__ void init_kernel(const float* __restrict__ x,
                            const float* __restrict__ conv_w,
                            const float* __restrict__ conv_b,
                            float* __restrict__ sar_ws,
                            float* __restrict__ coef_ws,
                            float* __restrict__ v0) {
    int t = blockIdx.x * blockDim.x + threadIdx.x;   // 0 .. B*S-1
    int b = t >> 12;
    int s = t & (S_SIZE - 1);
    int y = s >> 6, xx = s & 63;

    float acc = conv_b[0];
#pragma unroll
    for (int ic = 0; ic < 2; ++ic) {
        const float* xp = x + ((b * 2 + ic) << 12);
#pragma unroll
        for (int ky = 0; ky < 3; ++ky) {
            int yy = y + ky - 1;
            if (yy < 0 || yy >= IMSIZE) continue;
#pragma unroll
            for (int kx = 0; kx < 3; ++kx) {
                int xc = xx + kx - 1;
                if (xc < 0 || xc >= IMSIZE) continue;
                acc = fmaf(xp[(yy << 6) + xc], conv_w[(ic * 3 + ky) * 3 + kx], acc);
            }
        }
    }
    float x1 = x[((b * 2 + 1) << 12) + s];
    float coef = GAMMA * (1.0f - 0.1f * x1);

    int g = b >> 3, b8 = b & 7;
    int o = (((g << 12) + s) << 3) + b8;
    sar_ws[o]  = acc;
    coef_ws[o] = coef;
    v0[o]      = acc;
}

// pk[(s*8+a)*10 + c] = { byte offset idx*32, clamped prob }
__global__ void pack_kernel(const int* __restrict__ ds_state,
                            const int* __restrict__ ds_prob,
                            const float* __restrict__ pv,
                            int2* __restrict__ pk) {
    int i = blockIdx.x * blockDim.x + threadIdx.x;
    if (i >= S_SIZE * A_SZ * C_SZ) return;
    int idx = ds_state[i];
    float p = pv[ds_prob[i]];
    p = fminf(fmaxf(p, 0.0f), 1.0f);
    int2 e;
    e.x = idx << 5;                 // byte offset into [s*8+b] float LDS
    e.y = __float_as_int(p);
    pk[i] = e;
}

// One VI step. grid = 256 (blockIdx = slice*4+g), block = 512 = (w<<3)|a.
__global__ __launch_bounds__(512) void vi_kernel(const float* __restrict__ vin,
                                                 float* __restrict__ vout,
                                                 const float* __restrict__ sar_ws,
                                                 const float* __restrict__ coef_ws,
                                                 const int2* __restrict__ pk) {
    __shared__ float vld[8 * S_SIZE];   // 128 KiB
    const int g = blockIdx.x & 3;
    const int slice = blockIdx.x >> 2;
    const int tid = threadIdx.x;

    // ---- stage v (32768 floats) : global -> LDS direct, 16B per lane ----
    const float4* src4 = (const float4*)(vin + (g << 15));
    float4* dst4 = (float4*)vld;
#if __has_builtin(__builtin_amdgcn_global_load_lds)
#pragma unroll
    for (int r = 0; r < 16; ++r) {
        int i = tid + (r << 9);
        __builtin_amdgcn_global_load_lds(
            (const __attribute__((address_space(1))) void*)(src4 + i),
            (__attribute__((address_space(3))) void*)(dst4 + i), 16, 0, 0);
    }
#else
#pragma unroll
    for (int r = 0; r < 16; ++r) {
        int i = tid + (r << 9);
        dst4[i] = src4[i];
    }
#endif

    // ---- overlap: per-(s,a) transition row + sar/coef into registers ----
    const int w = tid >> 3, a = tid & 7;
    const int s = (slice << 6) + w;

    int4 er[5];   // 10 x (int2) = 5 x int4
    {
        const int4* rp = (const int4*)(pk + ((s << 3) + a) * C_SZ);
#pragma unroll
        for (int i = 0; i < 5; ++i) er[i] = rp[i];
    }
    float4 sar_lo, sar_hi, coef_lo, coef_hi;
    {
        const float4* sp = (const float4*)(sar_ws + (((g << 12) + s) << 3));
        const float4* cp = (const float4*)(coef_ws + (((g << 12) + s) << 3));
        sar_lo = sp[0]; sar_hi = sp[1];
        coef_lo = cp[0]; coef_hi = cp[1];
    }
    __syncthreads();

    // ---- gather-accumulate over c: 2 x ds_read_b128 per entry ----
    float4 acc_lo = {0.f, 0.f, 0.f, 0.f};
    float4 acc_hi = {0.f, 0.f, 0.f, 0.f};
    const char* vbase = (const char*)vld;
#pragma unroll
    for (int i = 0; i < 5; ++i) {
        {
            int off = er[i].x;
            float p = __int_as_float(er[i].y);
            float4 lo = *(const float4*)(vbase + off);
            float4 hi = *(const float4*)(vbase + off + 16);
            acc_lo.x = fmaf(p, lo.x, acc_lo.x); acc_lo.y = fmaf(p, lo.y, acc_lo.y);
            acc_lo.z = fmaf(p, lo.z, acc_lo.z); acc_lo.w = fmaf(p, lo.w, acc_lo.w);
            acc_hi.x = fmaf(p, hi.x, acc_hi.x); acc_hi.y = fmaf(p, hi.y, acc_hi.y);
            acc_hi.z = fmaf(p, hi.z, acc_hi.z); acc_hi.w = fmaf(p, hi.w, acc_hi.w);
        }
        {
            int off = er[i].z;
            float p = __int_as_float(er[i].w);
            float4 lo = *(const float4*)(vbase + off);
            float4 hi = *(const float4*)(vbase + off + 16);
            acc_lo.x = fmaf(p, lo.x, acc_lo.x); acc_lo.y = fmaf(p, lo.y, acc_lo.y);
            acc_lo.z = fmaf(p, lo.z, acc_lo.z); acc_lo.w = fmaf(p, lo.w, acc_lo.w);
            acc_hi.x = fmaf(p, hi.x, acc_hi.x); acc_hi.y = fmaf(p, hi.y, acc_hi.y);
            acc_hi.z = fmaf(p, hi.z, acc_hi.z); acc_hi.w = fmaf(p, hi.w, acc_hi.w);
        }
    }

    float q[8];
    q[0] = fmaf(coef_lo.x, acc_lo.x, sar_lo.x);
    q[1] = fmaf(coef_lo.y, acc_lo.y, sar_lo.y);
    q[2] = fmaf(coef_lo.z, acc_lo.z, sar_lo.z);
    q[3] = fmaf(coef_lo.w, acc_lo.w, sar_lo.w);
    q[4] = fmaf(coef_hi.x, acc_hi.x, sar_hi.x);
    q[5] = fmaf(coef_hi.y, acc_hi.y, sar_hi.y);
    q[6] = fmaf(coef_hi.z, acc_hi.z, sar_hi.z);
    q[7] = fmaf(coef_hi.w, acc_hi.w, sar_hi.w);

    // max over the 8 action-lanes (butterfly)
#pragma unroll
    for (int off = 1; off < 8; off <<= 1) {
#pragma unroll
        for (int b = 0; b < 8; ++b)
            q[b] = fmaxf(q[b], __shfl_xor(q[b], off, 8));
    }
    // lane a writes batch b = a
    float myv = q[0];
#pragma unroll
    for (int b = 1; b < 8; ++b)
        if (a == b) myv = q[b];
    vout[(g << 15) + (s << 3) + a] = myv;
}

// Final q30 at gathered states + fused linear + residual (raw tables, runs once)
__global__ void out_kernel(const float* __restrict__ v29,
                           const int* __restrict__ ds_state,
                           const int* __restrict__ ds_prob,
                           const float* __restrict__ pv,
                           const float* __restrict__ sar_ws,
                           const float* __restrict__ coef_ws,
                           const int* __restrict__ s1,
                           const int* __restrict__ s2,
                           const float* __restrict__ lin_w,
                           const float* __restrict__ lin_b,
                           float* __restrict__ out) {
    int t = blockIdx.x * blockDim.x + threadIdx.x;
    if (t >= B_SIZE * SB) return;
    int b = t >> 7;
    int s = s1[t] * IMSIZE + s2[t];
    int g = b >> 3, b8 = b & 7;
    int o = (((g << 12) + s) << 3) + b8;
    float sar = sar_ws[o];
    float coef = coef_ws[o];
    const float* vbase = v29 + (g << 15) + b8;

    float q[A_SZ];
#pragma unroll
    for (int a = 0; a < A_SZ; ++a) {
        float accq = 0.0f;
        int bb = (s * A_SZ + a) * C_SZ;
#pragma unroll
        for (int c = 0; c < C_SZ; ++c) {
            float p = pv[ds_prob[bb + c]];
            p = fminf(fmaxf(p, 0.0f), 1.0f);
            accq = fmaf(p, vbase[ds_state[bb + c] << 3], accq);
        }
        q[a] = fmaf(coef, accq, sar);
    }
#pragma unroll
    for (int i = 0; i < A_SZ; ++i) {
        float o2 = lin_b[i] + q[i];
#pragma unroll
        for (int a = 0; a < A_SZ; ++a)
            o2 = fmaf(q[a], lin_w[i * 8 + a], o2);
        out[t * 8 + i] = o2;
    }
}

extern "C" void kernel_launch(void* const* d_in, const int* in_sizes, int n_in,
                              void* d_out, int out_size, void* d_ws, size_t ws_size,
                              hipStream_t stream) {
    const float* x        = (const float*)d_in[0];
    const int*   s1       = (const int*)d_in[1];
    const int*   s2       = (const int*)d_in[2];
    const int*   ds_state = (const int*)d_in[3];
    const int*   ds_prob  = (const int*)d_in[4];
    const float* conv_w   = (const float*)d_in[5];
    const float* conv_b   = (const float*)d_in[6];
    const float* pv       = (const float*)d_in[7];
    const float* lin_w    = (const float*)d_in[8];
    const float* lin_b    = (const float*)d_in[9];
    float* out = (float*)d_out;

    const size_t VSZ = (size_t)B_SIZE * S_SIZE * 4;   // 512 KiB
    char* ws = (char*)d_ws;
    float* vA      = (float*)(ws);
    float* vB      = (float*)(ws + VSZ);
    float* sar_ws  = (float*)(ws + 2 * VSZ);
    float* coef_ws = (float*)(ws + 3 * VSZ);
    int2*  pk      = (int2*) (ws + 4 * VSZ);

    init_kernel<<<(B_SIZE * S_SIZE) / 256, 256, 0, stream>>>(
        x, conv_w, conv_b, sar_ws, coef_ws, vA);
    pack_kernel<<<(S_SIZE * A_SZ * C_SZ + 255) / 256, 256, 0, stream>>>(
        ds_state, ds_prob, pv, pk);

    float* vin = vA;
    float* vout = vB;
    for (int i = 0; i < VI_K - 1; ++i) {
        vi_kernel<<<256, 512, 0, stream>>>(vin, vout, sar_ws, coef_ws, pk);
        float* tmp = vin; vin = vout; vout = tmp;
    }

    out_kernel<<<(B_SIZE * SB + 255) / 256, 256, 0, stream>>>(
        vin, ds_state, ds_prob, pv, sar_ws, coef_ws, s1, s2, lin_w, lin_b, out);
}